// Round 1
// 2620.921 us; speedup vs baseline: 1.3309x; 1.3309x over previous
//
#include <hip/hip_runtime.h>

// SSMTrack: B=8, S=4096, H=1024, D=256
//   inp = x @ W_in + b_in                    (bf16 MFMA GEMM)
//   s_t = tanh(inp_t + s_{t-1} @ W_state + b_state)   (MFMA f16 scan, 1 WG/batch)
//   out = states @ W_out + b_out             (bf16 MFMA GEMM)

typedef float v4f __attribute__((ext_vector_type(4)));
typedef __bf16 bf16x4 __attribute__((ext_vector_type(4)));
typedef __bf16 bf16x8 __attribute__((ext_vector_type(8)));
typedef _Float16 h8 __attribute__((ext_vector_type(8)));

#define BARRIER_LGKM() asm volatile("s_waitcnt lgkmcnt(0)\n\ts_barrier" ::: "memory")

// ---------------------------------------------------------------- conversions
__global__ void cvt_f32_bf16_x4(const float* __restrict__ in,
                                __bf16* __restrict__ out, int n4) {
  int i = blockIdx.x * blockDim.x + threadIdx.x;
  if (i >= n4) return;
  v4f v = ((const v4f*)in)[i];
  bf16x4 o;
  o.x = (__bf16)v.x; o.y = (__bf16)v.y; o.z = (__bf16)v.z; o.w = (__bf16)v.w;
  ((bf16x4*)out)[i] = o;
}

// in: [K,N] f32 row-major  ->  out: [N,K] bf16 row-major (i.e. B^T)
__global__ void transpose_cvt(const float* __restrict__ in,
                              __bf16* __restrict__ out, int K, int N) {
  int i = blockIdx.x * blockDim.x + threadIdx.x;
  if (i >= K * N) return;
  int k = i / N;
  int n = i - k * N;
  out[(size_t)n * K + k] = (__bf16)in[i];
}

// ---------------------------------------------------------------- GEMM (bf16)
// C[M,N] (f32) = A[M,K](bf16, row-major) * B  where Bt[N,K] = B^T (bf16)
// One wave per 16x16 C-tile, fragments loaded straight from global.
// C/D: col = l&15, row = (l>>4)*4 + i   (m89-verified)
__global__ void gemm_bt(const __bf16* __restrict__ A,
                        const __bf16* __restrict__ Bt,
                        const float* __restrict__ bias,
                        float* __restrict__ C,
                        int M, int N, int K) {
  int wid  = (blockIdx.x * blockDim.x + threadIdx.x) >> 6;
  int lane = threadIdx.x & 63;
  int ntiles = N >> 4;
  int mt = wid / ntiles;          // nt inner so consecutive waves share A rows
  int nt = wid - mt * ntiles;
  if (mt * 16 >= M) return;
  int r = lane & 15;
  int q = lane >> 4;
  const __bf16* arow = A + (size_t)(mt * 16 + r) * K + q * 8;
  const __bf16* brow = Bt + (size_t)(nt * 16 + r) * K + q * 8;
  v4f acc = {0.f, 0.f, 0.f, 0.f};
  for (int k = 0; k < K; k += 32) {
    bf16x8 af = *(const bf16x8*)(arow + k);
    bf16x8 bf = *(const bf16x8*)(brow + k);
    acc = __builtin_amdgcn_mfma_f32_16x16x32_bf16(af, bf, acc, 0, 0, 0);
  }
  int col = nt * 16 + r;
  float bv = bias[col];
  size_t base = (size_t)(mt * 16 + q * 4) * N + col;
#pragma unroll
  for (int i = 0; i < 4; ++i) C[base + (size_t)i * N] = acc[i] + bv;
}

// ---------------------------------------------------------------- scan (MFMA)
// One block (256 threads = 4 waves) per batch. Each step is
//   s_t[256] = tanh(inp_t + s_{t-1} @ W_state + b_state)
// done as MFMA 16x16x32_f16 with ALL 16 A-rows aliased to the state vector
// (A-fragment LDS address depends only on lane>>4 -> 4-address broadcast,
// conflict-free). Wave w owns output n-tiles {4w..4w+3} (cols w*64..w*64+63)
// and holds W_state for those columns permanently in registers as f16
// B-fragments (128 VGPRs). Per wave-step: 8 ds_read_b128 (vs 32 in the
// fdot2 version -> 4x less DS-pipe pressure) + 32 MFMA. Bias + input are
// added post-MFMA on the selected row (all rows identical), so only one
// u-load per lane per step (2-deep prefetch). State ping-pongs between two
// f16 LDS buffers; single lgkm-only barrier per step (u-prefetch and the
// bf16 global state store stay in flight across it).
__global__ __launch_bounds__(256, 1) void scan_mfma(
    const float* __restrict__ inp,      // [B*S, 256] f32
    const float* __restrict__ Wst,      // [256, 256] f32
    const float* __restrict__ b_state,  // [256] f32
    __bf16* __restrict__ states,        // [B*S, 256] bf16 (out)
    int S) {
  const int tid = threadIdx.x;        // == output column this lane writes
  const int l = tid & 63;
  const int q = l >> 4;
  const int r = l & 15;
  const int w = tid >> 6;             // wave 0..3
  const int b = blockIdx.x;

  __shared__ __align__(16) _Float16 sbuf[2][256];

  // B-fragments for mfma_f32_16x16x32_f16: lane holds B[k][col] with
  // col = 16*tile + r, k = 32*c + 8*q + i. One-time f32->f16 convert.
  h8 bw0[8], bw1[8], bw2[8], bw3[8];
#pragma unroll
  for (int c = 0; c < 8; ++c) {
#pragma unroll
    for (int i = 0; i < 8; ++i) {
      const float* wr = Wst + (size_t)(32 * c + 8 * q + i) * 256 + w * 64 + r;
      bw0[c][i] = (_Float16)wr[0];
      bw1[c][i] = (_Float16)wr[16];
      bw2[c][i] = (_Float16)wr[32];
      bw3[c][i] = (_Float16)wr[48];
    }
  }

  const float bst = b_state[tid];
  const float* inpb = inp + (size_t)b * S * 256;
  __bf16* stb = states + (size_t)b * S * 256;

  sbuf[0][tid] = (_Float16)0.f;  // state0 = 0
  float u_cur = inpb[tid];                 // u for t=0
  float u_nxt = inpb[256 + tid];           // u for t=1 (S >= 2)
  __syncthreads();

  int cur = 0;
  for (int t = 0; t < S; ++t) {
    // prefetch u for t+2 so ~500cy of global latency hides under 2 steps
    float u_n2 = 0.f;
    if (t + 2 < S) u_n2 = inpb[(size_t)(t + 2) * 256 + tid];

    // A-fragments: address = 64*c + 16*q bytes -> 4 distinct addresses,
    // broadcast over 16-lane groups; all 16 A-rows = state (junk-free by
    // construction: every C row computes the same dot).
    const h8* sp = (const h8*)sbuf[cur];
    h8 af[8];
#pragma unroll
    for (int c = 0; c < 8; ++c) af[c] = sp[4 * c + q];

    v4f a0 = {0.f, 0.f, 0.f, 0.f};
    v4f a1 = a0, a2 = a0, a3 = a0;
#pragma unroll
    for (int c = 0; c < 8; ++c) {
      a0 = __builtin_amdgcn_mfma_f32_16x16x32_f16(af[c], bw0[c], a0, 0, 0, 0);
      a1 = __builtin_amdgcn_mfma_f32_16x16x32_f16(af[c], bw1[c], a1, 0, 0, 0);
      a2 = __builtin_amdgcn_mfma_f32_16x16x32_f16(af[c], bw2[c], a2, 0, 0, 0);
      a3 = __builtin_amdgcn_mfma_f32_16x16x32_f16(af[c], bw3[c], a3, 0, 0, 0);
    }
    // lane writes col = w*64 + l = 16*(4w+q) + r -> n-tile index q
    float x = (q == 0) ? a0[0] : (q == 1) ? a1[0] : (q == 2) ? a2[0] : a3[0];
    x += u_cur + bst;

    // tanh(x) = 1 - 2/(exp(2x)+1)
    float e = __expf(2.f * x);
    float sn = 1.f - 2.f * __builtin_amdgcn_rcpf(e + 1.f);

    cur ^= 1;
    sbuf[cur][tid] = (_Float16)sn;            // ds_write_b16
    stb[(size_t)t * 256 + tid] = (__bf16)sn;  // fire-and-forget global store
    u_cur = u_nxt;
    u_nxt = u_n2;
    BARRIER_LGKM();
  }
}

// ---------------------------------------------------------------- launch
extern "C" void kernel_launch(void* const* d_in, const int* in_sizes, int n_in,
                              void* d_out, int out_size, void* d_ws,
                              size_t ws_size, hipStream_t stream) {
  const float* x       = (const float*)d_in[0];  // [8,4096,1024]
  const float* W_in    = (const float*)d_in[1];  // [1024,256]
  const float* b_in    = (const float*)d_in[2];  // [256]
  const float* W_state = (const float*)d_in[3];  // [256,256]
  const float* b_state = (const float*)d_in[4];  // [256]
  const float* W_out   = (const float*)d_in[5];  // [256,1024]
  const float* b_out   = (const float*)d_in[6];  // [1024]
  float* out = (float*)d_out;                    // [8,4096,1024]

  const int B = 8, S = 4096, H = 1024, D = 256;
  const int M = B * S;  // 32768

  char* ws = (char*)d_ws;
  float*  inp    = (float*)(ws + 0);            // 32 MB  [M,D] f32
  __bf16* states = (__bf16*)(ws + 33554432);    // 16 MB  [M,D] bf16
  __bf16* xb     = (__bf16*)(ws + 50331648);    // 64 MB  [M,H] bf16
  __bf16* WinT   = (__bf16*)(ws + 117440512);   // 0.5 MB [D,H] bf16  (W_in^T)
  __bf16* WoutT  = (__bf16*)(ws + 117964800);   // 0.5 MB [H,D] bf16  (W_out^T)

  // conversions
  cvt_f32_bf16_x4<<<(M * H / 4 + 255) / 256, 256, 0, stream>>>(x, xb, M * H / 4);
  transpose_cvt<<<(H * D + 255) / 256, 256, 0, stream>>>(W_in, WinT, H, D);
  transpose_cvt<<<(D * H + 255) / 256, 256, 0, stream>>>(W_out, WoutT, D, H);

  // phase 1: inp = x @ W_in + b_in   (M=32768, N=256, K=1024)
  {
    int waves = (M / 16) * (D / 16);
    gemm_bt<<<waves / 4, 256, 0, stream>>>(xb, WinT, b_in, inp, M, D, H);
  }

  // phase 2: sequential scan, one block (4 waves) per batch
  scan_mfma<<<B, 256, 0, stream>>>(inp, W_state, b_state, states, S);

  // phase 3: out = states @ W_out + b_out   (M=32768, N=1024, K=256)
  {
    int waves = (M / 16) * (H / 16);
    gemm_bt<<<waves / 4, 256, 0, stream>>>(states, WoutT, b_out, out, M, H, D);
  }
}